// Round 3
// baseline (858.697 us; speedup 1.0000x reference)
//
#include <hip/hip_runtime.h>
#include <math.h>

typedef __attribute__((ext_vector_type(4))) float f32x4;
typedef __attribute__((ext_vector_type(8))) short bf16x8;
typedef __attribute__((ext_vector_type(4))) unsigned short u16x4;

__device__ __forceinline__ unsigned short f2bf(float f) {
  unsigned u = __builtin_bit_cast(unsigned, f);
  u += 0x7fffu + ((u >> 16) & 1u);
  return (unsigned short)(u >> 16);
}
__device__ __forceinline__ float bf2f(unsigned short s) {
  return __builtin_bit_cast(float, (unsigned)s << 16);
}
__device__ __forceinline__ float sigmoidf_(float x) { return 1.f / (1.f + __expf(-x)); }

// ---------------------------------------------------------------------------
// bf16-MFMA GEMM, 128x128 tile, BK=32, 4 waves, double-buffered LDS with
// 1-deep register prefetch. C[M,N] = A[M,K] @ B[N,K]^T (+bias), epilogues.
// ACAT/BCAT: K-concat (1st ptr for k<Ksplit, 2nd after; same dtype).
// z-split: blocks with z >= zs use "b" pointer set (A1b/B1b/bias1b/Cb), zz=z-zs.
// ABF16: A elements are bf16 (u16). OBF16: C written bf16 (EPI 0 only).
// EPI: 0 = (acc+bias)*scale ; 1 = acc+bias+P0+P1 ;
//      2 = (P2+P3+ce+sig(acc+bias)*(P1-ce))/3, ce=P0[row*256+(col&255)]
// ---------------------------------------------------------------------------
template <int ACAT, int BCAT, int EPI, int ABF16, int OBF16>
__global__ __launch_bounds__(256) void gemm_k(
    const void* __restrict__ A1, const void* __restrict__ A1b, int lda1, long aZ,
    const void* __restrict__ A2, int lda2, int Ksplit,
    const float* __restrict__ B1, const float* __restrict__ B1b, int ldb1, long bZ,
    const float* __restrict__ B2, int ldb2,
    const float* __restrict__ bias1, const float* __restrict__ bias1b, long biasZ,
    const float* __restrict__ bias2,
    void* __restrict__ C, void* __restrict__ Cb, int ldc, long cZ,
    int K, int zs, float scale,
    const float* __restrict__ P0, const float* __restrict__ P1,
    const float* __restrict__ P2, const float* __restrict__ P3) {
  __shared__ unsigned short As[2][128][32];
  __shared__ unsigned short Bs[2][128][32];
  const int t = threadIdx.x;
  const int lane = t & 63;
  const int wave = t >> 6;
  const int wr = wave >> 1, wc = wave & 1;
  const int bm = blockIdx.y, bn = blockIdx.x, z = blockIdx.z;

  const bool hi = z >= zs;
  const int zz = hi ? z - zs : z;
  const char* Abase = (const char*)(hi ? A1b : A1) + (long)zz * aZ * (ABF16 ? 2 : 4);
  const float* Bbase = (hi ? B1b : B1) + (long)zz * bZ;
  const float* biasp = hi ? bias1b : bias1;
  char* Czc = (char*)(hi ? Cb : C) + (long)zz * cZ * (OBF16 ? 2 : 4);

  const int ar = t >> 3;          // 0..31 (+32*i)
  const int bc = (t & 7) * 4;     // 0..28

  const int kIters = K >> 5;
  u16x4 Ra[4], Rb[4];

  auto loadT = [&](int kt) {
    const int k0 = kt << 5;
    const char* Ap; int ldA, kA;
    if (ACAT == 1 && k0 >= Ksplit) { Ap = (const char*)A2; ldA = lda2; kA = k0 - Ksplit; }
    else { Ap = Abase; ldA = lda1; kA = k0; }
    const float* Bp; int ldB, kB;
    if (BCAT == 1 && k0 >= Ksplit) { Bp = B2; ldB = ldb2; kB = k0 - Ksplit; }
    else { Bp = Bbase; ldB = ldb1; kB = k0; }
#pragma unroll
    for (int i = 0; i < 4; ++i) {
      const long aoff = ((long)bm * 128 + ar + 32 * i) * ldA + kA + bc;
      if (ABF16) {
        Ra[i] = *(const u16x4*)((const unsigned short*)Ap + aoff);
      } else {
        f32x4 v = *(const f32x4*)((const float*)Ap + aoff);
        u16x4 pk;
        pk[0] = f2bf(v[0]); pk[1] = f2bf(v[1]); pk[2] = f2bf(v[2]); pk[3] = f2bf(v[3]);
        Ra[i] = pk;
      }
      f32x4 bv = *(const f32x4*)(Bp + ((long)bn * 128 + ar + 32 * i) * ldB + kB + bc);
      u16x4 bp;
      bp[0] = f2bf(bv[0]); bp[1] = f2bf(bv[1]); bp[2] = f2bf(bv[2]); bp[3] = f2bf(bv[3]);
      Rb[i] = bp;
    }
  };

  loadT(0);

  f32x4 acc[4][4] = {};
  int p = 0;
  for (int kt = 0; kt < kIters; ++kt) {
    __syncthreads();  // buf[p] free to overwrite
#pragma unroll
    for (int i = 0; i < 4; ++i) {
      *(u16x4*)&As[p][ar + 32 * i][bc] = Ra[i];
      *(u16x4*)&Bs[p][ar + 32 * i][bc] = Rb[i];
    }
    if (kt + 1 < kIters) loadT(kt + 1);
    __syncthreads();  // buf[p] staged

    bf16x8 af[4], bfr[4];
#pragma unroll
    for (int mi = 0; mi < 4; ++mi)
      af[mi] = *(const bf16x8*)&As[p][wr * 64 + mi * 16 + (lane & 15)][(lane >> 4) * 8];
#pragma unroll
    for (int ni = 0; ni < 4; ++ni)
      bfr[ni] = *(const bf16x8*)&Bs[p][wc * 64 + ni * 16 + (lane & 15)][(lane >> 4) * 8];
#pragma unroll
    for (int mi = 0; mi < 4; ++mi)
#pragma unroll
      for (int ni = 0; ni < 4; ++ni)
        acc[mi][ni] = __builtin_amdgcn_mfma_f32_16x16x32_bf16(af[mi], bfr[ni], acc[mi][ni], 0, 0, 0);
    p ^= 1;
  }

  const int colb = bn * 128 + wc * 64;
  const int rowb = bm * 128 + wr * 64;
#pragma unroll
  for (int mi = 0; mi < 4; ++mi) {
#pragma unroll
    for (int ni = 0; ni < 4; ++ni) {
      f32x4 v = acc[mi][ni];
      const int col = colb + ni * 16 + (lane & 15);
      const int row0 = rowb + mi * 16 + ((lane >> 4) << 2);
      float bsum = 0.f;
      if (biasp) bsum += biasp[zz * biasZ + col];
      if (bias2) bsum += bias2[col];
#pragma unroll
      for (int q = 0; q < 4; ++q) {
        const long row = row0 + q;
        const long off = row * ldc + col;
        const float val = v[q] + bsum;
        if (EPI == 0) {
          if (OBF16) ((unsigned short*)Czc)[off] = f2bf(val * scale);
          else       ((float*)Czc)[off] = val * scale;
        } else if (EPI == 1) {
          ((float*)Czc)[off] = val + P0[off] + P1[off];
        } else {
          const float g = sigmoidf_(val);
          const float ce = P0[row * 256 + (col & 255)];
          const float ex = P1[off];
          ((float*)Czc)[off] = (P2[off] + P3[off] + ce + g * (ex - ce)) * (1.f / 3.f);
        }
      }
    }
  }
}

// 64x64 LDS-tiled transpose: out[n][d] = in[d][n], n = 1024
__global__ __launch_bounds__(256) void transpose_k(const float* __restrict__ in,
                                                   float* __restrict__ out, int n) {
  __shared__ float tile[64][65];
  const int tr = blockIdx.y, tc = blockIdx.x, t = threadIdx.x;
#pragma unroll
  for (int it = 0; it < 16; ++it) {
    int idx = t + 256 * it;
    int r = idx >> 6, c = idx & 63;
    tile[r][c] = in[(long)(tr * 64 + r) * n + tc * 64 + c];
  }
  __syncthreads();
#pragma unroll
  for (int it = 0; it < 16; ++it) {
    int idx = t + 256 * it;
    int rr = idx >> 6, cc = idx & 63;
    out[(long)(tc * 64 + rr) * n + tr * 64 + cc] = tile[cc][rr];
  }
}

// LSTM elementwise: gates [B,4096] order i,f,g,o
__global__ __launch_bounds__(256) void lstm_k(const float* __restrict__ gates,
                                              const float* __restrict__ c_in,
                                              float* __restrict__ c_out,
                                              float* __restrict__ h_ws,
                                              float* __restrict__ h_out) {
  const long i4 = (long)blockIdx.x * 256 + threadIdx.x;
  const long b = i4 >> 8;
  const int j = (int)(i4 & 255) * 4;
  const float* gb = gates + b * 4096;
  f32x4 gi = *(const f32x4*)(gb + j);
  f32x4 gf = *(const f32x4*)(gb + 1024 + j);
  f32x4 gg = *(const f32x4*)(gb + 2048 + j);
  f32x4 go = *(const f32x4*)(gb + 3072 + j);
  f32x4 cv = *(const f32x4*)(c_in + i4 * 4);
  f32x4 cn, hv;
#pragma unroll
  for (int q = 0; q < 4; ++q) {
    float cc = sigmoidf_(gf[q]) * cv[q] + sigmoidf_(gi[q]) * tanhf(gg[q]);
    cn[q] = cc;
    hv[q] = sigmoidf_(go[q]) * tanhf(cc);
  }
  *(f32x4*)(c_out + i4 * 4) = cn;
  *(f32x4*)(h_ws + i4 * 4) = hv;
  *(f32x4*)(h_out + i4 * 4) = hv;
}

// router: rw[b,:] = softmax(h_lstm[b]@Wrout^T + brout), one wave per b
__global__ __launch_bounds__(64) void router_k(const float* __restrict__ hl,
                                               const float* __restrict__ Wr,
                                               const float* __restrict__ br,
                                               float* __restrict__ rw) {
  const int b = blockIdx.x, lane = threadIdx.x;
  float a0 = 0.f, a1 = 0.f;
  for (int k = lane; k < 1024; k += 64) {
    float h = hl[(long)b * 1024 + k];
    a0 += h * Wr[k];
    a1 += h * Wr[1024 + k];
  }
#pragma unroll
  for (int m = 32; m >= 1; m >>= 1) {
    a0 += __shfl_xor(a0, m);
    a1 += __shfl_xor(a1, m);
  }
  if (lane == 0) {
    float z0 = a0 + br[0], z1 = a1 + br[1];
    float mx = fmaxf(z0, z1);
    float e0 = __expf(z0 - mx), e1 = __expf(z1 - mx);
    float s = e0 + e1;
    rw[2 * b] = e0 / s;
    rw[2 * b + 1] = e1 / s;
  }
}

__global__ __launch_bounds__(256) void combine_k(const float* __restrict__ so,
                                                 const float* __restrict__ eo,
                                                 const float* __restrict__ rw,
                                                 float* __restrict__ ra) {
  const long i4 = (long)blockIdx.x * 256 + threadIdx.x;
  const long b = i4 >> 8;
  const float w0 = rw[2 * b], w1 = rw[2 * b + 1];
  f32x4 s = *(const f32x4*)(so + i4 * 4);
  f32x4 e = *(const f32x4*)(eo + i4 * 4);
  f32x4 r;
#pragma unroll
  for (int q = 0; q < 4; ++q) r[q] = w0 * s[q] + w1 * e[q];
  *(f32x4*)(ra + i4 * 4) = r;
}

// ---------------------------------------------------------------------------
// Fused attention (Lq=1), self+ext merged (blockIdx.y). K/V staged in LDS as
// bf16 (pitch 140 shorts -> only 2-way bank aliasing, free), double-buffered,
// 1-deep register prefetch. qt is bf16; mix written bf16. LDS ~18.9 KB ->
// 8 blocks/CU (32 waves/CU).
// ---------------------------------------------------------------------------
__global__ __launch_bounds__(256) void attn2_k(
    const float* __restrict__ memK, const float* __restrict__ memV,
    const float* __restrict__ extK, const float* __restrict__ extV,
    const float* __restrict__ hl,
    const unsigned short* __restrict__ qtS, const unsigned short* __restrict__ qtE,
    unsigned short* __restrict__ mixS, unsigned short* __restrict__ mixE,
    float* __restrict__ ts) {
  const int NB = 2048, H = 1024;
  __shared__ unsigned short tile[2][32][140];
  __shared__ float p_s[8][32];
  const int b = blockIdx.x;
  const bool self = blockIdx.y == 0;
  const int t = threadIdx.x;
  const int head = t >> 5, l = t & 31;
  const unsigned short* qrow = (self ? qtS : qtE) + (long)b * 8192 + (long)head * 1024;
  unsigned short* mix = (self ? mixS : mixE) + (long)b * 8192;

  const float* baseK[4];
  const float* baseV[4];
  int rr[4], cc4[4];
#pragma unroll
  for (int it = 0; it < 4; ++it) {
    int f = t + 256 * it;
    int r = f >> 5, c4 = f & 31;
    rr[it] = r; cc4[it] = c4;
    if (self) {
      baseK[it] = (r < 31) ? (memK + ((long)(r + 1) * NB + b) * H) : (hl + (long)b * H);
      baseV[it] = (r < 31) ? (memV + ((long)(r + 1) * NB + b) * H) : (hl + (long)b * H);
    } else {
      baseK[it] = extK + ((long)r * NB + b) * H;
      baseV[it] = extV + ((long)r * NB + b) * H;
    }
  }

  f32x4 R[4];
#pragma unroll
  for (int it = 0; it < 4; ++it) R[it] = *(const f32x4*)(baseK[it] + cc4[it] * 4);

  float sc = 0.f;
  int p = 0;
  for (int ch = 0; ch < 8; ++ch) {
    __syncthreads();  // buf[p] free
#pragma unroll
    for (int it = 0; it < 4; ++it) {
      u16x4 kp;
      kp[0] = f2bf(R[it][0]); kp[1] = f2bf(R[it][1]);
      kp[2] = f2bf(R[it][2]); kp[3] = f2bf(R[it][3]);
      *(u16x4*)&tile[p][rr[it]][cc4[it] * 4] = kp;
    }
    if (ch < 7) {
#pragma unroll
      for (int it = 0; it < 4; ++it)
        R[it] = *(const f32x4*)(baseK[it] + (ch + 1) * 128 + cc4[it] * 4);
    } else {
#pragma unroll
      for (int it = 0; it < 4; ++it)  // prefetch V chunk 0 under softmax
        R[it] = *(const f32x4*)(baseV[it] + cc4[it] * 4);
    }
    __syncthreads();  // buf[p] staged
    if (self && t < 128) {
      float s = 0.f;
#pragma unroll
      for (int lr = 0; lr < 32; ++lr) s += bf2f(tile[p][lr][t]);
      ts[(long)b * H + ch * 128 + t] = s * (1.f / 32.f);
    }
#pragma unroll 8
    for (int c = 0; c < 32; ++c) {
      u16x4 kv = *(const u16x4*)&tile[p][l][c * 4];
      u16x4 qv = *(const u16x4*)(qrow + ch * 128 + c * 4);
      sc += bf2f(kv[0]) * bf2f(qv[0]) + bf2f(kv[1]) * bf2f(qv[1]) +
            bf2f(kv[2]) * bf2f(qv[2]) + bf2f(kv[3]) * bf2f(qv[3]);
    }
    p ^= 1;
  }

  float mx = sc;
#pragma unroll
  for (int m = 16; m >= 1; m >>= 1) mx = fmaxf(mx, __shfl_xor(mx, m, 32));
  float pr = __expf(sc - mx);
  float sum = pr;
#pragma unroll
  for (int m = 16; m >= 1; m >>= 1) sum += __shfl_xor(sum, m, 32);
  pr /= sum;
  p_s[head][l] = pr;  // made visible by the barrier inside the V loop

  for (int ch = 0; ch < 8; ++ch) {
    __syncthreads();
#pragma unroll
    for (int it = 0; it < 4; ++it) {
      u16x4 vp;
      vp[0] = f2bf(R[it][0]); vp[1] = f2bf(R[it][1]);
      vp[2] = f2bf(R[it][2]); vp[3] = f2bf(R[it][3]);
      *(u16x4*)&tile[p][rr[it]][cc4[it] * 4] = vp;
    }
    if (ch < 7) {
#pragma unroll
      for (int it = 0; it < 4; ++it)
        R[it] = *(const f32x4*)(baseV[it] + (ch + 1) * 128 + cc4[it] * 4);
    }
    __syncthreads();
    float a0 = 0.f, a1 = 0.f, a2 = 0.f, a3 = 0.f;
#pragma unroll
    for (int lr = 0; lr < 32; ++lr) {
      float pw = p_s[head][lr];
      u16x4 vv = *(const u16x4*)&tile[p][lr][l * 4];
      a0 += pw * bf2f(vv[0]);
      a1 += pw * bf2f(vv[1]);
      a2 += pw * bf2f(vv[2]);
      a3 += pw * bf2f(vv[3]);
    }
    u16x4 mo;
    mo[0] = f2bf(a0); mo[1] = f2bf(a1); mo[2] = f2bf(a2); mo[3] = f2bf(a3);
    *(u16x4*)(mix + (long)head * 1024 + ch * 128 + l * 4) = mo;
    p ^= 1;
  }
}

extern "C" void kernel_launch(void* const* d_in, const int* in_sizes, int n_in,
                              void* d_out, int out_size, void* d_ws, size_t ws_size,
                              hipStream_t stream) {
  const float* x    = (const float*)d_in[0];
  const float* h    = (const float*)d_in[1];
  const float* c    = (const float*)d_in[2];
  const float* memK = (const float*)d_in[3];
  const float* memV = (const float*)d_in[4];
  const float* extK = (const float*)d_in[5];
  const float* extV = (const float*)d_in[6];
  const float* W_ih = (const float*)d_in[7];
  const float* W_hh = (const float*)d_in[8];
  const float* b_ih = (const float*)d_in[9];
  const float* b_hh = (const float*)d_in[10];
  const float* sWq = (const float*)d_in[11];
  const float* sbq = (const float*)d_in[12];
  const float* sWk = (const float*)d_in[13];
  const float* sWv = (const float*)d_in[15];
  const float* sbv = (const float*)d_in[16];
  const float* sWo = (const float*)d_in[17];
  const float* sbo = (const float*)d_in[18];
  const float* cWq = (const float*)d_in[19];
  const float* cbq = (const float*)d_in[20];
  const float* cWk = (const float*)d_in[21];
  const float* cWv = (const float*)d_in[23];
  const float* cbv = (const float*)d_in[24];
  const float* cWo = (const float*)d_in[25];
  const float* cbo = (const float*)d_in[26];
  const float* Wres = (const float*)d_in[27];
  const float* bres = (const float*)d_in[28];
  const float* Wrout = (const float*)d_in[29];
  const float* brout = (const float*)d_in[30];
  const float* Wcomp = (const float*)d_in[31];
  const float* bcomp = (const float*)d_in[32];
  const float* Wexp = (const float*)d_in[33];
  const float* bexp = (const float*)d_in[34];
  const float* Wgate = (const float*)d_in[35];
  const float* bgate = (const float*)d_in[36];
  (void)in_sizes; (void)n_in; (void)out_size; (void)ws_size;

  float* out = (float*)d_out;
  float* w = (float*)d_ws;
  const long M1 = 1024 * 1024;
  float* gates   = w;            // [2048,4096] f32
  float* hl      = w + 8 * M1;   // [2048,1024] f32
  unsigned short* qsS = (unsigned short*)(w + 10 * M1);  // [2048,1024] bf16
  unsigned short* qsE = (unsigned short*)(w + 12 * M1);
  float* wkTs    = w + 14 * M1;  // [1024,1024] f32
  float* wkTc    = w + 15 * M1;
  unsigned short* qtS = (unsigned short*)(w + 16 * M1);  // [2048,8192] bf16
  unsigned short* qtE = (unsigned short*)(w + 32 * M1);
  unsigned short* mixS = (unsigned short*)(w + 48 * M1); // [2048,8192] bf16
  unsigned short* mixE = (unsigned short*)(w + 64 * M1);
  float* ts      = w + 80 * M1;  // [2048,1024] f32
  unsigned short* attnS = (unsigned short*)(w + 82 * M1);  // [2048,1024] bf16
  unsigned short* attnE = (unsigned short*)(w + 84 * M1);
  float* selfO   = w + 86 * M1;  // f32
  float* extO    = w + 88 * M1;  // f32
  float* rw      = w + 90 * M1;  // [2048,2]
  float* rattn   = w + 91 * M1;  // f32
  float* routed  = w + 93 * M1;  // f32
  float* comp    = w + 95 * M1;  // [2048,256] f32
  float* expd    = w + 96 * M1;  // f32

  float* hFinal_out = out;
  float* hl_out     = out + 2 * M1;
  float* cn_out     = out + 4 * M1;

  const float scaleq = 0.08838834764831845f;  // 1/sqrt(128)
  const int ZBIG = 1 << 30;
  dim3 blk(256);
  const float* nf = nullptr;

  transpose_k<<<dim3(16, 16), blk, 0, stream>>>(sWk, wkTs, 1024);
  transpose_k<<<dim3(16, 16), blk, 0, stream>>>(cWk, wkTc, 1024);

  // gates = x@W_ih^T + h@W_hh^T + b_ih + b_hh  (K-concat both sides)
  gemm_k<1, 1, 0, 0, 0><<<dim3(32, 16, 1), blk, 0, stream>>>(
      x, nullptr, 1024, 0, h, 1024, 1024,
      W_ih, nf, 1024, 0, W_hh, 1024,
      b_ih, nf, 0, b_hh,
      gates, nullptr, 4096, 0,
      2048, ZBIG, 1.f, nf, nf, nf, nf);

  lstm_k<<<2048, blk, 0, stream>>>(gates, c, cn_out, hl, hl_out);

  // qs (self z=0, ext z=1), scaled, bf16 out
  gemm_k<0, 0, 0, 0, 1><<<dim3(8, 16, 2), blk, 0, stream>>>(
      hl, hl, 1024, 0, nullptr, 0, 0,
      sWq, cWq, 1024, 0, nf, 0,
      sbq, cbq, 0, nf,
      qsS, qsE, 1024, 0,
      1024, 1, scaleq, nf, nf, nf, nf);

  // qt[b,h,k] = sum_d qs[b,h*128+d]*WkT[k,h*128+d]; z: 0-7 self, 8-15 ext
  gemm_k<0, 0, 0, 1, 1><<<dim3(8, 16, 16), blk, 0, stream>>>(
      qsS, qsE, 1024, 128, nullptr, 0, 0,
      wkTs, wkTc, 1024, 128, nf, 0,
      nf, nf, 0, nf,
      qtS, qtE, 8192, 1024,
      128, 8, 1.f, nf, nf, nf, nf);

  // fused attention, self+ext
  attn2_k<<<dim3(2048, 2), blk, 0, stream>>>(memK, memV, extK, extV, hl,
                                             qtS, qtE, mixS, mixE, ts);

  // attn[b, h*128+d] = mix[b,h,:]@Wv_h^T + bv ; z: 0-7 self, 8-15 ext; bf16 out
  gemm_k<0, 0, 0, 1, 1><<<dim3(1, 16, 16), blk, 0, stream>>>(
      mixS, mixE, 8192, 1024, nullptr, 0, 0,
      sWv, cWv, 1024, 131072, nf, 0,
      sbv, cbv, 128, nf,
      attnS, attnE, 1024, 128,
      1024, 8, 1.f, nf, nf, nf, nf);

  // output projections (z=0 self, z=1 ext), bf16 A, f32 out
  gemm_k<0, 0, 0, 1, 0><<<dim3(8, 16, 2), blk, 0, stream>>>(
      attnS, attnE, 1024, 0, nullptr, 0, 0,
      sWo, cWo, 1024, 0, nf, 0,
      sbo, cbo, 0, nf,
      selfO, extO, 1024, 0,
      1024, 1, 1.f, nf, nf, nf, nf);

  router_k<<<2048, dim3(64), 0, stream>>>(hl, Wrout, brout, rw);
  combine_k<<<2048, blk, 0, stream>>>(selfO, extO, rw, rattn);

  // routed = h_lstm + rattn + rattn@Wres^T + bres
  gemm_k<0, 0, 1, 0, 0><<<dim3(8, 16, 1), blk, 0, stream>>>(
      rattn, nullptr, 1024, 0, nullptr, 0, 0,
      Wres, nf, 1024, 0, nf, 0,
      bres, nf, 0, nf,
      routed, nullptr, 1024, 0,
      1024, ZBIG, 1.f, hl, rattn, nf, nf);

  // compressed / expanded
  gemm_k<0, 0, 0, 0, 0><<<dim3(2, 16, 1), blk, 0, stream>>>(
      ts, nullptr, 1024, 0, nullptr, 0, 0,
      Wcomp, nf, 1024, 0, nf, 0,
      bcomp, nf, 0, nf,
      comp, nullptr, 256, 0,
      1024, ZBIG, 1.f, nf, nf, nf, nf);
  gemm_k<0, 0, 0, 0, 0><<<dim3(8, 16, 1), blk, 0, stream>>>(
      comp, nullptr, 256, 0, nullptr, 0, 0,
      Wexp, nf, 256, 0, nf, 0,
      bexp, nf, 0, nf,
      expd, nullptr, 1024, 0,
      256, ZBIG, 1.f, nf, nf, nf, nf);

  // gate GEMM (A = [x | routed] K-concat) + fused final epilogue
  gemm_k<1, 0, 2, 0, 0><<<dim3(8, 16, 1), blk, 0, stream>>>(
      x, nullptr, 1024, 0, routed, 1024, 1024,
      Wgate, nf, 2048, 0, nf, 0,
      bgate, nf, 0, nf,
      hFinal_out, nullptr, 1024, 0,
      2048, ZBIG, 1.f, comp, expd, hl, routed);
}

// Round 4
// 784.653 us; speedup vs baseline: 1.0944x; 1.0944x over previous
//
#include <hip/hip_runtime.h>
#include <math.h>

typedef __attribute__((ext_vector_type(4))) float f32x4;
typedef __attribute__((ext_vector_type(8))) short bf16x8;
typedef __attribute__((ext_vector_type(4))) unsigned short u16x4;

__device__ __forceinline__ unsigned short f2bf(float f) {
  unsigned u = __builtin_bit_cast(unsigned, f);
  u += 0x7fffu + ((u >> 16) & 1u);
  return (unsigned short)(u >> 16);
}
__device__ __forceinline__ float bf2f(unsigned short s) {
  return __builtin_bit_cast(float, (unsigned)s << 16);
}
__device__ __forceinline__ float sigmoidf_(float x) { return 1.f / (1.f + __expf(-x)); }

// ---------------------------------------------------------------------------
// bf16-MFMA GEMM, 128xTN tile (TN=128 or 64), BK=32, 4 waves, double-buffered
// LDS + 1-deep register prefetch, bijective XCD swizzle (grid product %8==0).
// C[M,N] = A[M,K] @ B[N,K]^T (+bias).
// ACAT/BCAT: K-concat (1st ptr k<Ksplit, 2nd after). z-split: z>=zs -> "b" set.
// ABF16: A is bf16. OBF16: C bf16 (EPI 0/3).
// EPI 0: (val)*scale
// EPI 1: val + P0[off] + P1[off]
// EPI 2: (P2+P3+ce+sig(val)*(P1-ce))/3, ce=P0[row*256+(col&255)]
// EPI 3: val * P0[2*row+hi]                       (rw-scaled, bf16 out)
// EPI 4: val + P2[2*row]*P0[col] + P2[2*row+1]*P1[col]
// ---------------------------------------------------------------------------
template <int TN, int ACAT, int BCAT, int EPI, int ABF16, int OBF16>
__global__ __launch_bounds__(256) void gemm_k(
    const void* __restrict__ A1, const void* __restrict__ A1b, int lda1, long aZ,
    const void* __restrict__ A2, int lda2, int Ksplit,
    const float* __restrict__ B1, const float* __restrict__ B1b, int ldb1, long bZ,
    const float* __restrict__ B2, int ldb2,
    const float* __restrict__ bias1, const float* __restrict__ bias1b, long biasZ,
    const float* __restrict__ bias2,
    void* __restrict__ C, void* __restrict__ Cb, int ldc, long cZ,
    int K, int zs, float scale,
    const float* __restrict__ P0, const float* __restrict__ P1,
    const float* __restrict__ P2, const float* __restrict__ P3) {
  constexpr int NBI = TN / 32;  // B staging iters == frag cols per wave
  __shared__ unsigned short As[2][128][32];
  __shared__ unsigned short Bs[2][TN][32];
  const int t = threadIdx.x;
  const int lane = t & 63;
  const int wave = t >> 6;
  const int wr = wave >> 1, wc = wave & 1;

  // bijective XCD swizzle over the full linear grid
  const unsigned gx = gridDim.x, gy = gridDim.y;
  unsigned L = blockIdx.x + gx * (blockIdx.y + gy * blockIdx.z);
  const unsigned nwg = gx * gy * gridDim.z;
  L = (L & 7u) * (nwg >> 3) + (L >> 3);
  const int bn = L % gx;
  const unsigned r1 = L / gx;
  const int bm = r1 % gy;
  const int z = r1 / gy;

  const bool hi = z >= zs;
  const int zz = hi ? z - zs : z;
  const char* Abase = (const char*)(hi ? A1b : A1) + (long)zz * aZ * (ABF16 ? 2 : 4);
  const float* Bbase = (hi ? B1b : B1) + (long)zz * bZ;
  const float* biasp = hi ? bias1b : bias1;
  char* Czc = (char*)(hi ? Cb : C) + (long)zz * cZ * (OBF16 ? 2 : 4);

  const int ar = t >> 3;       // 0..31 (+32*i)
  const int bc = (t & 7) * 4;  // 0..28

  const int kIters = K >> 5;
  u16x4 Ra[4], Rb[NBI];

  auto loadT = [&](int kt) {
    const int k0 = kt << 5;
    const char* Ap; int ldA, kA;
    if (ACAT == 1 && k0 >= Ksplit) { Ap = (const char*)A2; ldA = lda2; kA = k0 - Ksplit; }
    else { Ap = Abase; ldA = lda1; kA = k0; }
    const float* Bp; int ldB, kB;
    if (BCAT == 1 && k0 >= Ksplit) { Bp = B2; ldB = ldb2; kB = k0 - Ksplit; }
    else { Bp = Bbase; ldB = ldb1; kB = k0; }
#pragma unroll
    for (int i = 0; i < 4; ++i) {
      const long aoff = ((long)bm * 128 + ar + 32 * i) * ldA + kA + bc;
      if (ABF16) {
        Ra[i] = *(const u16x4*)((const unsigned short*)Ap + aoff);
      } else {
        f32x4 v = *(const f32x4*)((const float*)Ap + aoff);
        u16x4 pk;
        pk[0] = f2bf(v[0]); pk[1] = f2bf(v[1]); pk[2] = f2bf(v[2]); pk[3] = f2bf(v[3]);
        Ra[i] = pk;
      }
    }
#pragma unroll
    for (int i = 0; i < NBI; ++i) {
      f32x4 bv = *(const f32x4*)(Bp + ((long)bn * TN + ar + 32 * i) * ldB + kB + bc);
      u16x4 bp;
      bp[0] = f2bf(bv[0]); bp[1] = f2bf(bv[1]); bp[2] = f2bf(bv[2]); bp[3] = f2bf(bv[3]);
      Rb[i] = bp;
    }
  };

  loadT(0);

  f32x4 acc[4][NBI] = {};
  int p = 0;
  for (int kt = 0; kt < kIters; ++kt) {
    __syncthreads();
#pragma unroll
    for (int i = 0; i < 4; ++i) *(u16x4*)&As[p][ar + 32 * i][bc] = Ra[i];
#pragma unroll
    for (int i = 0; i < NBI; ++i) *(u16x4*)&Bs[p][ar + 32 * i][bc] = Rb[i];
    if (kt + 1 < kIters) loadT(kt + 1);
    __syncthreads();

    bf16x8 af[4], bfr[NBI];
#pragma unroll
    for (int mi = 0; mi < 4; ++mi)
      af[mi] = *(const bf16x8*)&As[p][wr * 64 + mi * 16 + (lane & 15)][(lane >> 4) * 8];
#pragma unroll
    for (int ni = 0; ni < NBI; ++ni)
      bfr[ni] = *(const bf16x8*)&Bs[p][wc * (TN / 2) + ni * 16 + (lane & 15)][(lane >> 4) * 8];
#pragma unroll
    for (int mi = 0; mi < 4; ++mi)
#pragma unroll
      for (int ni = 0; ni < NBI; ++ni)
        acc[mi][ni] = __builtin_amdgcn_mfma_f32_16x16x32_bf16(af[mi], bfr[ni], acc[mi][ni], 0, 0, 0);
    p ^= 1;
  }

  const int colb = bn * TN + wc * (TN / 2);
  const int rowb = bm * 128 + wr * 64;
#pragma unroll
  for (int mi = 0; mi < 4; ++mi) {
#pragma unroll
    for (int ni = 0; ni < NBI; ++ni) {
      f32x4 v = acc[mi][ni];
      const int col = colb + ni * 16 + (lane & 15);
      const int row0 = rowb + mi * 16 + ((lane >> 4) << 2);
      float bsum = 0.f;
      if (biasp) bsum += biasp[zz * biasZ + col];
      if (bias2) bsum += bias2[col];
#pragma unroll
      for (int q = 0; q < 4; ++q) {
        const long row = row0 + q;
        const long off = row * ldc + col;
        const float val = v[q] + bsum;
        if (EPI == 0) {
          if (OBF16) ((unsigned short*)Czc)[off] = f2bf(val * scale);
          else       ((float*)Czc)[off] = val * scale;
        } else if (EPI == 1) {
          ((float*)Czc)[off] = val + P0[off] + P1[off];
        } else if (EPI == 2) {
          const float g = sigmoidf_(val);
          const float ce = P0[row * 256 + (col & 255)];
          const float ex = P1[off];
          ((float*)Czc)[off] = (P2[off] + P3[off] + ce + g * (ex - ce)) * (1.f / 3.f);
        } else if (EPI == 3) {
          ((unsigned short*)Czc)[off] = f2bf(val * P0[2 * row + (hi ? 1 : 0)]);
        } else {
          ((float*)Czc)[off] = val + P2[2 * row] * P0[col] + P2[2 * row + 1] * P1[col];
        }
      }
    }
  }
}

// 64x64 LDS-tiled transpose, z selects (in,out) pair. out[n][d] = in[d][n]
__global__ __launch_bounds__(256) void transpose_k(const float* __restrict__ in0,
                                                   float* __restrict__ out0,
                                                   const float* __restrict__ in1,
                                                   float* __restrict__ out1, int n) {
  __shared__ float tile[64][65];
  const float* in = blockIdx.z ? in1 : in0;
  float* out = blockIdx.z ? out1 : out0;
  const int tr = blockIdx.y, tc = blockIdx.x, t = threadIdx.x;
#pragma unroll
  for (int it = 0; it < 16; ++it) {
    int idx = t + 256 * it;
    int r = idx >> 6, c = idx & 63;
    tile[r][c] = in[(long)(tr * 64 + r) * n + tc * 64 + c];
  }
  __syncthreads();
#pragma unroll
  for (int it = 0; it < 16; ++it) {
    int idx = t + 256 * it;
    int rr = idx >> 6, cc = idx & 63;
    out[(long)(tc * 64 + rr) * n + tr * 64 + cc] = tile[cc][rr];
  }
}

// LSTM elementwise + fused router (block == one batch row b)
__global__ __launch_bounds__(256) void lstm_k(const float* __restrict__ gates,
                                              const float* __restrict__ c_in,
                                              const float* __restrict__ Wr,
                                              const float* __restrict__ br,
                                              float* __restrict__ c_out,
                                              float* __restrict__ h_ws,
                                              float* __restrict__ h_out,
                                              float* __restrict__ rw) {
  const int b = blockIdx.x, t = threadIdx.x;
  const long base = (long)b * 1024 + t * 4;
  const float* gb = gates + (long)b * 4096 + t * 4;
  f32x4 gi = *(const f32x4*)(gb);
  f32x4 gf = *(const f32x4*)(gb + 1024);
  f32x4 gg = *(const f32x4*)(gb + 2048);
  f32x4 go = *(const f32x4*)(gb + 3072);
  f32x4 cv = *(const f32x4*)(c_in + base);
  f32x4 cn, hv;
#pragma unroll
  for (int q = 0; q < 4; ++q) {
    float cc = sigmoidf_(gf[q]) * cv[q] + sigmoidf_(gi[q]) * tanhf(gg[q]);
    cn[q] = cc;
    hv[q] = sigmoidf_(go[q]) * tanhf(cc);
  }
  *(f32x4*)(c_out + base) = cn;
  *(f32x4*)(h_ws + base) = hv;
  *(f32x4*)(h_out + base) = hv;
  // fused router
  f32x4 w0 = *(const f32x4*)(Wr + t * 4);
  f32x4 w1 = *(const f32x4*)(Wr + 1024 + t * 4);
  float a0 = hv[0] * w0[0] + hv[1] * w0[1] + hv[2] * w0[2] + hv[3] * w0[3];
  float a1 = hv[0] * w1[0] + hv[1] * w1[1] + hv[2] * w1[2] + hv[3] * w1[3];
#pragma unroll
  for (int m = 32; m >= 1; m >>= 1) {
    a0 += __shfl_xor(a0, m);
    a1 += __shfl_xor(a1, m);
  }
  __shared__ float red[8];
  if ((t & 63) == 0) { red[t >> 6] = a0; red[4 + (t >> 6)] = a1; }
  __syncthreads();
  if (t == 0) {
    float z0 = red[0] + red[1] + red[2] + red[3] + br[0];
    float z1 = red[4] + red[5] + red[6] + red[7] + br[1];
    float mx = fmaxf(z0, z1);
    float e0 = __expf(z0 - mx), e1 = __expf(z1 - mx);
    float s = e0 + e1;
    rw[2 * b] = e0 / s;
    rw[2 * b + 1] = e1 / s;
  }
}

// ---------------------------------------------------------------------------
// Fused attention (Lq=1), self+ext via blockIdx.y, MFMA for scores AND mix.
// Scores: S[32l,16h(8 used)] = K_chunk(LDS, GEMM-frag layout) x qt(global bf16)
//   accumulated per-wave over its k-slice; cross-wave reduce via Sp; softmax.
// Mix: mix[16h(8),128d] per chunk = P(LDS bf16) x Vt(LDS, transposed bf16).
// ts (self only) = column mean of staged K.
// ---------------------------------------------------------------------------
__global__ __launch_bounds__(256) void attn3_k(
    const float* __restrict__ memK, const float* __restrict__ memV,
    const float* __restrict__ extK, const float* __restrict__ extV,
    const float* __restrict__ hl,
    const unsigned short* __restrict__ qtS, const unsigned short* __restrict__ qtE,
    unsigned short* __restrict__ mixS, unsigned short* __restrict__ mixE,
    float* __restrict__ ts) {
  const int NB = 2048, H = 1024;
  __shared__ __align__(16) unsigned short sreg[2][128][36];  // V layout; K aliases
  __shared__ float Sp[4][32][17];
  __shared__ unsigned short P_lds[16][32];
  unsigned short* KT = &sreg[0][0][0];  // K: [buf*4096 + j*1024 + r*32 + k2]

  const int b = blockIdx.x;
  const bool self = blockIdx.y == 0;
  const int t = threadIdx.x;
  const int lane = t & 63;
  const int w = t >> 6;

  // ---- K staging map (r, c4) ----
  const float* baseK[4];
  int rrA[4], cc4[4];
#pragma unroll
  for (int it = 0; it < 4; ++it) {
    int f = t + 256 * it;
    int r = f >> 5, c4 = f & 31;
    rrA[it] = r; cc4[it] = c4;
    if (self) baseK[it] = (r < 31) ? (memK + ((long)(r + 1) * NB + b) * H) : (hl + (long)b * H);
    else      baseK[it] = extK + ((long)r * NB + b) * H;
  }
  // ---- V staging map (l-pair, dgrp) ----
  const int l2 = t & 15, dgrp = t >> 4;
  const float* baseV0;
  const float* baseV1;
  {
    int r0 = 2 * l2, r1v = 2 * l2 + 1;
    if (self) {
      baseV0 = memV + ((long)(r0 + 1) * NB + b) * H;
      baseV1 = (r1v < 31) ? (memV + ((long)(r1v + 1) * NB + b) * H) : (hl + (long)b * H);
    } else {
      baseV0 = extV + ((long)r0 * NB + b) * H;
      baseV1 = extV + ((long)r1v * NB + b) * H;
    }
  }

  const unsigned short* qtb = (self ? qtS : qtE) + (long)b * 8192 + (lane & 7) * 1024;
  unsigned short* mixp = (self ? mixS : mixE) + (long)b * 8192;

  f32x4 R[4];
#pragma unroll
  for (int it = 0; it < 4; ++it) R[it] = *(const f32x4*)(baseK[it] + cc4[it] * 4);
  bf16x8 bq = *(const bf16x8*)(qtb + w * 32 + ((lane >> 4) * 8));

  f32x4 accS[2] = {};
  int p = 0;
  // ================= K phase =================
  for (int ch = 0; ch < 8; ++ch) {
    __syncthreads();
#pragma unroll
    for (int it = 0; it < 4; ++it)
      *(u16x4*)(KT + p * 4096 + (cc4[it] >> 3) * 1024 + rrA[it] * 32 + (cc4[it] & 7) * 4) =
          (u16x4){f2bf(R[it][0]), f2bf(R[it][1]), f2bf(R[it][2]), f2bf(R[it][3])};
    if (ch < 7) {
#pragma unroll
      for (int it = 0; it < 4; ++it)
        R[it] = *(const f32x4*)(baseK[it] + (ch + 1) * 128 + cc4[it] * 4);
    } else {  // prefetch V chunk 0
      R[0] = *(const f32x4*)(baseV0 + dgrp * 8);
      R[1] = *(const f32x4*)(baseV0 + dgrp * 8 + 4);
      R[2] = *(const f32x4*)(baseV1 + dgrp * 8);
      R[3] = *(const f32x4*)(baseV1 + dgrp * 8 + 4);
    }
    __syncthreads();
    bf16x8 bq_cur = bq;
    if (ch < 7) bq = *(const bf16x8*)(qtb + (ch + 1) * 128 + w * 32 + ((lane >> 4) * 8));
    if (self && t < 128) {
      float s = 0.f;
      const unsigned short* kc = KT + p * 4096 + (t >> 5) * 1024 + (t & 31);
#pragma unroll
      for (int lr = 0; lr < 32; ++lr) s += bf2f(kc[lr * 32]);
      ts[(long)b * H + ch * 128 + t] = s * (1.f / 32.f);
    }
#pragma unroll
    for (int mi = 0; mi < 2; ++mi) {
      bf16x8 af = *(const bf16x8*)(KT + p * 4096 + w * 1024 + (mi * 16 + (lane & 15)) * 32 +
                                   ((lane >> 4) * 8));
      accS[mi] = __builtin_amdgcn_mfma_f32_16x16x32_bf16(af, bq_cur, accS[mi], 0, 0, 0);
    }
    p ^= 1;
  }
  // ---- cross-wave reduce + softmax ----
#pragma unroll
  for (int mi = 0; mi < 2; ++mi)
#pragma unroll
    for (int q = 0; q < 4; ++q)
      Sp[w][mi * 16 + (lane >> 4) * 4 + q][lane & 15] = accS[mi][q];
  __syncthreads();
  {
    const int head = t >> 5, l = t & 31;
    float S = Sp[0][l][head] + Sp[1][l][head] + Sp[2][l][head] + Sp[3][l][head];
    float mx = S;
#pragma unroll
    for (int m = 16; m >= 1; m >>= 1) mx = fmaxf(mx, __shfl_xor(mx, m, 32));
    float pr = __expf(S - mx);
    float sum = pr;
#pragma unroll
    for (int m = 16; m >= 1; m >>= 1) sum += __shfl_xor(sum, m, 32);
    pr /= sum;
    P_lds[head][l] = f2bf(pr);
    P_lds[8 + head][l] = 0;  // zero pad rows 8..15
  }
  // ================= V phase =================
  for (int ch = 0; ch < 8; ++ch) {
    __syncthreads();
#pragma unroll
    for (int e = 0; e < 4; ++e) {
      unsigned lo0 = (unsigned)f2bf(R[0][e]) | ((unsigned)f2bf(R[2][e]) << 16);
      unsigned lo1 = (unsigned)f2bf(R[1][e]) | ((unsigned)f2bf(R[3][e]) << 16);
      *(unsigned*)&sreg[p][dgrp * 8 + e][2 * l2] = lo0;
      *(unsigned*)&sreg[p][dgrp * 8 + 4 + e][2 * l2] = lo1;
    }
    if (ch < 7) {
      R[0] = *(const f32x4*)(baseV0 + (ch + 1) * 128 + dgrp * 8);
      R[1] = *(const f32x4*)(baseV0 + (ch + 1) * 128 + dgrp * 8 + 4);
      R[2] = *(const f32x4*)(baseV1 + (ch + 1) * 128 + dgrp * 8);
      R[3] = *(const f32x4*)(baseV1 + (ch + 1) * 128 + dgrp * 8 + 4);
    }
    __syncthreads();
    bf16x8 pa = *(const bf16x8*)&P_lds[lane & 15][(lane >> 4) * 8];
#pragma unroll
    for (int i = 0; i < 2; ++i) {
      const int dbase = w * 32 + i * 16;
      const unsigned short* vb = &sreg[p][dbase + (lane & 15)][(lane >> 4) * 8];
      union { unsigned long long q[2]; bf16x8 v; } uu;
      uu.q[0] = *(const unsigned long long*)vb;
      uu.q[1] = *(const unsigned long long*)(vb + 4);
      f32x4 o = __builtin_amdgcn_mfma_f32_16x16x32_bf16(pa, uu.v, (f32x4){0.f, 0.f, 0.f, 0.f},
                                                        0, 0, 0);
      if (lane < 32) {
        const int d = ch * 128 + dbase + (lane & 15);
        const int h0 = (lane >> 4) * 4;
#pragma unroll
        for (int q = 0; q < 4; ++q) mixp[(long)(h0 + q) * 1024 + d] = f2bf(o[q]);
      }
    }
    p ^= 1;
  }
}

extern "C" void kernel_launch(void* const* d_in, const int* in_sizes, int n_in,
                              void* d_out, int out_size, void* d_ws, size_t ws_size,
                              hipStream_t stream) {
  const float* x    = (const float*)d_in[0];
  const float* h    = (const float*)d_in[1];
  const float* c    = (const float*)d_in[2];
  const float* memK = (const float*)d_in[3];
  const float* memV = (const float*)d_in[4];
  const float* extK = (const float*)d_in[5];
  const float* extV = (const float*)d_in[6];
  const float* W_ih = (const float*)d_in[7];
  const float* W_hh = (const float*)d_in[8];
  const float* b_ih = (const float*)d_in[9];
  const float* b_hh = (const float*)d_in[10];
  const float* sWq = (const float*)d_in[11];
  const float* sbq = (const float*)d_in[12];
  const float* sWk = (const float*)d_in[13];
  const float* sWv = (const float*)d_in[15];
  const float* sbv = (const float*)d_in[16];
  const float* sWo = (const float*)d_in[17];
  const float* sbo = (const float*)d_in[18];
  const float* cWq = (const float*)d_in[19];
  const float* cbq = (const float*)d_in[20];
  const float* cWk = (const float*)d_in[21];
  const float* cWv = (const float*)d_in[23];
  const float* cbv = (const float*)d_in[24];
  const float* cWo = (const float*)d_in[25];
  const float* cbo = (const float*)d_in[26];
  const float* Wres = (const float*)d_in[27];
  const float* bres = (const float*)d_in[28];
  const float* Wrout = (const float*)d_in[29];
  const float* brout = (const float*)d_in[30];
  const float* Wcomp = (const float*)d_in[31];
  const float* bcomp = (const float*)d_in[32];
  const float* Wexp = (const float*)d_in[33];
  const float* bexp = (const float*)d_in[34];
  const float* Wgate = (const float*)d_in[35];
  const float* bgate = (const float*)d_in[36];
  (void)in_sizes; (void)n_in; (void)out_size; (void)ws_size;

  float* out = (float*)d_out;
  float* w = (float*)d_ws;
  const long M1 = 1024 * 1024;
  float* gates   = w;            // [2048,4096] f32
  float* hl      = w + 8 * M1;   // [2048,1024] f32
  unsigned short* qsS = (unsigned short*)(w + 10 * M1);  // [2048,1024] bf16
  unsigned short* qsE = (unsigned short*)(w + 12 * M1);
  float* wkTs    = w + 14 * M1;  // [1024,1024] f32
  float* wkTc    = w + 15 * M1;
  unsigned short* qtS = (unsigned short*)(w + 16 * M1);  // [2048,8192] bf16
  unsigned short* qtE = (unsigned short*)(w + 32 * M1);
  unsigned short* mixS = (unsigned short*)(w + 48 * M1); // [2048,8192] bf16
  unsigned short* mixE = (unsigned short*)(w + 64 * M1);
  float* ts      = w + 80 * M1;  // [2048,1024] f32
  unsigned short* attnS = (unsigned short*)(w + 82 * M1);  // [2048,1024] bf16 (rw-scaled)
  unsigned short* attnE = (unsigned short*)(w + 84 * M1);
  float* rw      = w + 90 * M1;  // [2048,2]
  float* rattn   = w + 91 * M1;  // [2048,1024] f32
  float* routed  = w + 93 * M1;
  float* comp    = w + 95 * M1;  // [2048,256] f32
  float* expd    = w + 96 * M1;

  float* hFinal_out = out;
  float* hl_out     = out + 2 * M1;
  float* cn_out     = out + 4 * M1;

  const float scaleq = 0.08838834764831845f;  // 1/sqrt(128)
  const int ZBIG = 1 << 30;
  dim3 blk(256);
  const float* nf = nullptr;

  // gates = x@W_ih^T + h@W_hh^T + b_ih + b_hh
  gemm_k<128, 1, 1, 0, 0, 0><<<dim3(32, 16, 1), blk, 0, stream>>>(
      x, nullptr, 1024, 0, h, 1024, 1024,
      W_ih, nf, 1024, 0, W_hh, 1024,
      b_ih, nf, 0, b_hh,
      gates, nullptr, 4096, 0,
      2048, ZBIG, 1.f, nf, nf, nf, nf);

  transpose_k<<<dim3(16, 16, 2), blk, 0, stream>>>(sWk, wkTs, cWk, wkTc, 1024);

  lstm_k<<<2048, blk, 0, stream>>>(gates, c, Wrout, brout, cn_out, hl, hl_out, rw);

  // qs (z=0 self, z=1 ext), scaled, bf16 out
  gemm_k<128, 0, 0, 0, 0, 1><<<dim3(8, 16, 2), blk, 0, stream>>>(
      hl, hl, 1024, 0, nullptr, 0, 0,
      sWq, cWq, 1024, 0, nf, 0,
      sbq, cbq, 0, nf,
      qsS, qsE, 1024, 0,
      1024, 1, scaleq, nf, nf, nf, nf);

  // qt[b,h,k] = sum_d qs[b,h*128+d]*WkT[k,h*128+d]; z: 0-7 self, 8-15 ext
  gemm_k<128, 0, 0, 0, 1, 1><<<dim3(8, 16, 16), blk, 0, stream>>>(
      qsS, qsE, 1024, 128, nullptr, 0, 0,
      wkTs, wkTc, 1024, 128, nf, 0,
      nf, nf, 0, nf,
      qtS, qtE, 8192, 1024,
      128, 8, 1.f, nf, nf, nf, nf);

  // fused attention (MFMA scores + MFMA mix + ts)
  attn3_k<<<dim3(2048, 2), blk, 0, stream>>>(memK, memV, extK, extV, hl,
                                             qtS, qtE, mixS, mixE, ts);

  // attn'[b,h*128+d] = (mix@Wv_h^T + bv) * rw ; z: 0-7 self, 8-15 ext; bf16
  gemm_k<64, 0, 0, 3, 1, 1><<<dim3(2, 16, 16), blk, 0, stream>>>(
      mixS, mixE, 8192, 1024, nullptr, 0, 0,
      sWv, cWv, 1024, 131072, nf, 0,
      sbv, cbv, 128, nf,
      attnS, attnE, 1024, 128,
      1024, 8, 1.f, rw, nf, nf, nf);

  // rattn = [w0*attnS | w1*attnE] @ [sWo;cWo]^T + w0*sbo + w1*cbo
  gemm_k<64, 1, 1, 4, 1, 0><<<dim3(16, 16, 1), blk, 0, stream>>>(
      attnS, nullptr, 1024, 0, attnE, 1024, 1024,
      sWo, nf, 1024, 0, cWo, 1024,
      nf, nf, 0, nf,
      rattn, nullptr, 1024, 0,
      2048, ZBIG, 1.f, sbo, cbo, rw, nf);

  // routed = h_lstm + rattn + rattn@Wres^T + bres
  gemm_k<64, 0, 0, 1, 0, 0><<<dim3(16, 16, 1), blk, 0, stream>>>(
      rattn, nullptr, 1024, 0, nullptr, 0, 0,
      Wres, nf, 1024, 0, nf, 0,
      bres, nf, 0, nf,
      routed, nullptr, 1024, 0,
      1024, ZBIG, 1.f, hl, rattn, nf, nf);

  // compressed / expanded
  gemm_k<64, 0, 0, 0, 0, 0><<<dim3(4, 16, 1), blk, 0, stream>>>(
      ts, nullptr, 1024, 0, nullptr, 0, 0,
      Wcomp, nf, 1024, 0, nf, 0,
      bcomp, nf, 0, nf,
      comp, nullptr, 256, 0,
      1024, ZBIG, 1.f, nf, nf, nf, nf);
  gemm_k<64, 0, 0, 0, 0, 0><<<dim3(16, 16, 1), blk, 0, stream>>>(
      comp, nullptr, 256, 0, nullptr, 0, 0,
      Wexp, nf, 256, 0, nf, 0,
      bexp, nf, 0, nf,
      expd, nullptr, 1024, 0,
      256, ZBIG, 1.f, nf, nf, nf, nf);

  // gate GEMM (A = [x | routed]) + fused final epilogue
  gemm_k<64, 1, 0, 2, 0, 0><<<dim3(16, 16, 1), blk, 0, stream>>>(
      x, nullptr, 1024, 0, routed, 1024, 1024,
      Wgate, nf, 2048, 0, nf, 0,
      bgate, nf, 0, nf,
      hFinal_out, nullptr, 1024, 0,
      2048, ZBIG, 1.f, comp, expd, hl, routed);
}